// Round 1
// baseline (240.798 us; speedup 1.0000x reference)
//
#include <hip/hip_runtime.h>
#include <math.h>

// ---------------------------------------------------------------------------
// FPSANConv2d: out = conv3x3(x, Qt(w)) + b + sigmoid(gate)*(conv3x3(x, Qt(w_child)) + b_child)
// Fused: W_eff = Qt(w) + g*Qt(w_child) (bf16), b_eff = b + g*b_child, ONE conv.
// Conv as implicit GEMM on mfma_f32_16x16x32_bf16.
//   N=16, C=64, H=W=128, K=3x3, pad 1, stride 1.
// ---------------------------------------------------------------------------

typedef __attribute__((ext_vector_type(8))) short short8;   // 8 bf16 (4 VGPRs)
typedef __attribute__((ext_vector_type(4))) short short4v;  // 4 bf16
typedef __attribute__((ext_vector_type(4))) float float4v;  // MFMA C/D frag

#define CIP 72  // padded ci stride (elems) in LDS: 144 B, multiple of 16 B

__device__ inline unsigned short f2bf(float f) {
  union { float f; unsigned u; } v; v.f = f;
  unsigned u = v.u;
  return (unsigned short)((u + 0x7FFFu + ((u >> 16) & 1u)) >> 16);  // RNE
}

// ---- prep 1: sum |w|, |w_child| (f64 accumulate for scale determinism) ----
__global__ void reduce_abs(const float* __restrict__ w, const float* __restrict__ wc,
                           double* __restrict__ sums) {
  int i = blockIdx.x * 256 + threadIdx.x;  // grid covers exactly 36864
  float a = fabsf(w[i]);
  float c = fabsf(wc[i]);
#pragma unroll
  for (int off = 32; off > 0; off >>= 1) {
    a += __shfl_down(a, off);
    c += __shfl_down(c, off);
  }
  if ((threadIdx.x & 63) == 0) {
    atomicAdd(&sums[0], (double)a);
    atomicAdd(&sums[1], (double)c);
  }
}

// ---- prep 2: ternary-quantize both weights, combine with gate, emit bf16 ----
// Output layout wq[tap][oc][ci] (tap = kh*3+kw) for MFMA B-fragment reads.
__global__ void quant_combine(const float* __restrict__ w, const float* __restrict__ wc,
                              const float* __restrict__ b, const float* __restrict__ bc,
                              const float* __restrict__ gate, const double* __restrict__ sums,
                              unsigned short* __restrict__ wq, float* __restrict__ beff) {
  const float sw = fmaxf((float)(sums[0] * (1.0 / 36864.0)), 1e-5f);
  const float sc = fmaxf((float)(sums[1] * (1.0 / 36864.0)), 1e-5f);
  const float g = 1.0f / (1.0f + expf(-gate[0]));
  int idx = blockIdx.x * 256 + threadIdx.x;  // (tap, oc, ci)
  int tap = idx >> 12;
  int oc = (idx >> 6) & 63;
  int ci = idx & 63;
  int src = oc * 576 + ci * 9 + tap;  // OIHW flat
  float q1 = fminf(1.f, fmaxf(-1.f, rintf(w[src] / sw))) * sw;   // round-half-even like jnp.round
  float q2 = fminf(1.f, fmaxf(-1.f, rintf(wc[src] / sc))) * sc;
  wq[idx] = f2bf(q1 + g * q2);
  if (idx < 64) beff[idx] = b[idx] + g * bc[idx];
}

// ---- main conv: one block per (n, h) output row (128 pixels x 64 oc) ----
__global__ __launch_bounds__(256, 2) void conv_mfma(
    const float* __restrict__ x, const unsigned short* __restrict__ wq,
    const float* __restrict__ beff, float* __restrict__ out) {
  // LDS: 3 halo rows x 130 cols x 64 ci (bf16), ci-contiguous, zero-padded borders
  __shared__ unsigned short xs[3 * 130 * CIP];  // 56160 B -> 2 blocks/CU

  const int bid = blockIdx.x;
  const int n = bid >> 7;    // image
  const int h = bid & 127;   // output row
  const int tid = threadIdx.x;

  // ---- stage x rows h-1..h+1 into LDS, transposed to [r][c][ci], bf16 ----
#pragma unroll
  for (int r = 0; r < 3; ++r) {
    int row = h + r - 1;
    bool rok = (unsigned)row < 128u;
    for (int j = tid; j < 16 * 130; j += 256) {  // 16 ci-quads x 130 cols
      int ci4 = j / 130;
      int c = j - ci4 * 130;
      int ci = ci4 << 2;
      int ww = c - 1;  // global col
      float v0 = 0.f, v1 = 0.f, v2 = 0.f, v3 = 0.f;
      if (rok && (unsigned)ww < 128u) {
        const float* xp = x + (((n * 64 + ci) * 128 + row) * 128 + ww);
        v0 = xp[0];
        v1 = xp[16384];
        v2 = xp[32768];
        v3 = xp[49152];
      }
      short4v pk;
      pk[0] = (short)f2bf(v0);
      pk[1] = (short)f2bf(v1);
      pk[2] = (short)f2bf(v2);
      pk[3] = (short)f2bf(v3);
      *(short4v*)&xs[(r * 130 + c) * CIP + ci] = pk;
    }
  }
  __syncthreads();

  // ---- implicit GEMM: wave tile = 32 pixels x 64 oc ----
  const int lane = tid & 63;
  const int wv = tid >> 6;
  const int wbase = wv * 32;          // pixel base for this wave
  const int ln15 = lane & 15;         // A: m; B: n(oc) within quad
  const int koff = (lane >> 4) << 3;  // k offset within K=32 chunk

  float4v acc[2][4] = {};  // [m-frag][oc-quad]

#pragma unroll
  for (int tap = 0; tap < 9; ++tap) {
    const int dh = tap / 3;       // constant-folded (loop unrolled)
    const int dw = tap - dh * 3;
    const unsigned short* wt = wq + tap * 4096;
    const int abase0 = (dh * 130 + wbase + dw + ln15) * CIP + koff;
    const int abase1 = abase0 + 16 * CIP;
#pragma unroll
    for (int cc = 0; cc < 64; cc += 32) {
      short8 a0 = *(const short8*)&xs[abase0 + cc];
      short8 a1 = *(const short8*)&xs[abase1 + cc];
      const unsigned short* wp = wt + ln15 * 64 + cc + koff;
      short8 b0 = *(const short8*)(wp);
      short8 b1 = *(const short8*)(wp + 16 * 64);
      short8 b2 = *(const short8*)(wp + 32 * 64);
      short8 b3 = *(const short8*)(wp + 48 * 64);
      acc[0][0] = __builtin_amdgcn_mfma_f32_16x16x32_bf16(a0, b0, acc[0][0], 0, 0, 0);
      acc[1][0] = __builtin_amdgcn_mfma_f32_16x16x32_bf16(a1, b0, acc[1][0], 0, 0, 0);
      acc[0][1] = __builtin_amdgcn_mfma_f32_16x16x32_bf16(a0, b1, acc[0][1], 0, 0, 0);
      acc[1][1] = __builtin_amdgcn_mfma_f32_16x16x32_bf16(a1, b1, acc[1][1], 0, 0, 0);
      acc[0][2] = __builtin_amdgcn_mfma_f32_16x16x32_bf16(a0, b2, acc[0][2], 0, 0, 0);
      acc[1][2] = __builtin_amdgcn_mfma_f32_16x16x32_bf16(a1, b2, acc[1][2], 0, 0, 0);
      acc[0][3] = __builtin_amdgcn_mfma_f32_16x16x32_bf16(a0, b3, acc[0][3], 0, 0, 0);
      acc[1][3] = __builtin_amdgcn_mfma_f32_16x16x32_bf16(a1, b3, acc[1][3], 0, 0, 0);
    }
  }

  // ---- epilogue: C/D layout col=lane&15 (oc), row=(lane>>4)*4+reg (pixel) ----
  const int rq = lane >> 4;
  float bias[4];
#pragma unroll
  for (int q = 0; q < 4; ++q) bias[q] = beff[q * 16 + ln15];
#pragma unroll
  for (int mf = 0; mf < 2; ++mf) {
#pragma unroll
    for (int q = 0; q < 4; ++q) {
      float4v v = acc[mf][q] + bias[q];
      int oc = q * 16 + ln15;
      float* op = out + (((n * 64 + oc) * 128 + h) * 128 + wbase + mf * 16 + rq * 4);
      *(float4v*)op = v;
    }
  }
}

extern "C" void kernel_launch(void* const* d_in, const int* in_sizes, int n_in,
                              void* d_out, int out_size, void* d_ws, size_t ws_size,
                              hipStream_t stream) {
  const float* x = (const float*)d_in[0];
  const float* w = (const float*)d_in[1];
  const float* b = (const float*)d_in[2];
  const float* wc = (const float*)d_in[3];
  const float* bc = (const float*)d_in[4];
  const float* gate = (const float*)d_in[5];

  // workspace layout: wq bf16[9*64*64] | beff f32[64] | sums f64[2]
  unsigned short* wq = (unsigned short*)d_ws;
  float* beff = (float*)((char*)d_ws + 73728);
  double* sums = (double*)((char*)d_ws + 73984);

  hipMemsetAsync(sums, 0, 2 * sizeof(double), stream);
  reduce_abs<<<144, 256, 0, stream>>>(w, wc, sums);
  quant_combine<<<144, 256, 0, stream>>>(w, wc, b, bc, gate, sums, wq, beff);
  conv_mfma<<<2048, 256, 0, stream>>>(x, wq, beff, (float*)d_out);
}

// Round 2
// 231.601 us; speedup vs baseline: 1.0397x; 1.0397x over previous
//
#include <hip/hip_runtime.h>
#include <math.h>

// ---------------------------------------------------------------------------
// FPSANConv2d: out = conv3x3(x, Qt(w)) + b + sigmoid(gate)*(conv3x3(x, Qt(w_child)) + b_child)
// Fused: W_eff = Qt(w) + g*Qt(w_child) (bf16), b_eff = b + g*b_child, ONE conv.
//
// Round 2 structure:
//   k1 reduce_abs      : 1-block deterministic f64 reduce (no atomics, no memset)
//   k2 quant_combine   : ternary-quantize + gate-combine -> wq[tap][oc][ci] bf16
//   k3 transpose_x     : NCHW f32 -> zero-padded NHWC bf16 x_p[n][130][130][64]
//   k4 conv_mfma       : implicit GEMM, A/B fragments loaded DIRECTLY from global
//                        (16B contiguous per lane), no LDS, no barrier.
// ---------------------------------------------------------------------------

typedef __attribute__((ext_vector_type(8))) short short8;   // 8 bf16 (4 VGPRs)
typedef __attribute__((ext_vector_type(4))) float float4v;  // MFMA C/D frag

__device__ inline unsigned short f2bf(float f) {
  union { float f; unsigned u; } v; v.f = f;
  unsigned u = v.u;
  return (unsigned short)((u + 0x7FFFu + ((u >> 16) & 1u)) >> 16);  // RNE
}

// ---- k1: deterministic |w| sums, one block (no atomics -> no serialization) ----
__global__ __launch_bounds__(1024) void reduce_abs(const float* __restrict__ w,
                                                   const float* __restrict__ wc,
                                                   double* __restrict__ sums) {
  double a = 0.0, c = 0.0;
  for (int i = threadIdx.x; i < 36864; i += 1024) {
    a += (double)fabsf(w[i]);
    c += (double)fabsf(wc[i]);
  }
#pragma unroll
  for (int off = 32; off > 0; off >>= 1) {
    a += __shfl_down(a, off);
    c += __shfl_down(c, off);
  }
  __shared__ double sa[16], sc[16];
  int wv = threadIdx.x >> 6;
  if ((threadIdx.x & 63) == 0) { sa[wv] = a; sc[wv] = c; }
  __syncthreads();
  if (threadIdx.x == 0) {
    double ta = 0.0, tc = 0.0;
#pragma unroll
    for (int i = 0; i < 16; ++i) { ta += sa[i]; tc += sc[i]; }
    sums[0] = ta; sums[1] = tc;
  }
}

// ---- k2: ternary-quantize both weights, combine with gate, emit bf16 ----
// wq[tap][oc][ci], tap = kh*3+kw : ci-contiguous for 16B B-fragment loads.
__global__ void quant_combine(const float* __restrict__ w, const float* __restrict__ wc,
                              const float* __restrict__ b, const float* __restrict__ bc,
                              const float* __restrict__ gate, const double* __restrict__ sums,
                              unsigned short* __restrict__ wq, float* __restrict__ beff) {
  const float sw = fmaxf((float)(sums[0] * (1.0 / 36864.0)), 1e-5f);
  const float sc = fmaxf((float)(sums[1] * (1.0 / 36864.0)), 1e-5f);
  const float g = 1.0f / (1.0f + expf(-gate[0]));
  int idx = blockIdx.x * 256 + threadIdx.x;  // (tap, oc, ci)
  int tap = idx >> 12;
  int oc = (idx >> 6) & 63;
  int ci = idx & 63;
  int src = oc * 576 + ci * 9 + tap;  // OIHW flat
  float q1 = fminf(1.f, fmaxf(-1.f, rintf(w[src] / sw))) * sw;
  float q2 = fminf(1.f, fmaxf(-1.f, rintf(wc[src] / sc))) * sc;
  wq[idx] = f2bf(q1 + g * q2);
  if (idx < 64) beff[idx] = b[idx] + g * bc[idx];
}

// ---- k3: NCHW f32 -> zero-padded NHWC bf16  x_p[n][hp 0..129][cp 0..129][ci] ----
// One block per (n, hp). Border rows/cols written as zeros each call (ws is poisoned).
__global__ __launch_bounds__(256) void transpose_x(const float* __restrict__ x,
                                                   unsigned short* __restrict__ xp) {
  const int bid = blockIdx.x;            // n*130 + hp
  const int n = bid / 130;
  const int hp = bid - n * 130;
  unsigned short* dst = xp + (size_t)(n * 130 + hp) * (130 * 64);
  const int tid = threadIdx.x;

  if (hp == 0 || hp == 129) {            // zero whole padded row (1040 x 16B)
    for (int j = tid; j < 1040; j += 256) ((short8*)dst)[j] = (short8)0;
    return;
  }
  const int h = hp - 1;
  __shared__ unsigned short tile[128 * 72];  // [c][ci], pad 72 keeps 16B-aligned reads

  const float* src = x + (size_t)n * 64 * 16384 + h * 128;
  for (int k = tid; k < 8192; k += 256) {   // coalesced reads: c inner
    int ci = k >> 7;
    int c = k & 127;
    tile[c * 72 + ci] = f2bf(src[ci * 16384 + c]);
  }
  // zero col borders (cp=0 and cp=129): 8 x 16B each
  if (tid < 8) ((short8*)dst)[tid] = (short8)0;
  else if (tid < 16) ((short8*)dst)[1032 + (tid - 8)] = (short8)0;
  __syncthreads();
  // interior: contiguous 16B writes, 16B-aligned LDS reads
  for (int j = tid; j < 1024; j += 256) {
    int c = j >> 3;
    int ciq = j & 7;
    short8 v = *(const short8*)&tile[c * 72 + ciq * 8];
    ((short8*)dst)[8 + j] = v;  // col cp = c+1
  }
}

// ---- k4: conv as implicit GEMM, fragments straight from global (no LDS) ----
// Block = (n, h): 128 pixels x 64 oc. 4 waves x (32 px x 64 oc).
__global__ __launch_bounds__(256, 4) void conv_mfma(
    const unsigned short* __restrict__ xp, const unsigned short* __restrict__ wq,
    const float* __restrict__ beff, float* __restrict__ out) {
  const int bid = blockIdx.x;
  const int n = bid >> 7;
  const int h = bid & 127;
  const int tid = threadIdx.x;
  const int lane = tid & 63;
  const int wv = tid >> 6;
  const int wbase = wv * 32;
  const int ln15 = lane & 15;
  const int koff = (lane >> 4) << 3;

  // padded row hp = h + dh corresponds to input row h + dh - 1
  const unsigned short* xrow = xp + (size_t)(n * 130 + h) * (130 * 64);

  float4v acc[2][4] = {};

#pragma unroll
  for (int tap = 0; tap < 9; ++tap) {
    const int dh = tap / 3;
    const int dw = tap - dh * 3;
    const unsigned short* ap = xrow + (dh * 130 + wbase + dw + ln15) * 64 + koff;
    const unsigned short* wp = wq + tap * 4096 + ln15 * 64 + koff;
#pragma unroll
    for (int cc = 0; cc < 64; cc += 32) {
      short8 a0 = *(const short8*)(ap + cc);
      short8 a1 = *(const short8*)(ap + cc + 1024);   // +16 pixels
      short8 b0 = *(const short8*)(wp + cc);
      short8 b1 = *(const short8*)(wp + cc + 1024);   // +16 oc
      short8 b2 = *(const short8*)(wp + cc + 2048);
      short8 b3 = *(const short8*)(wp + cc + 3072);
      acc[0][0] = __builtin_amdgcn_mfma_f32_16x16x32_bf16(a0, b0, acc[0][0], 0, 0, 0);
      acc[1][0] = __builtin_amdgcn_mfma_f32_16x16x32_bf16(a1, b0, acc[1][0], 0, 0, 0);
      acc[0][1] = __builtin_amdgcn_mfma_f32_16x16x32_bf16(a0, b1, acc[0][1], 0, 0, 0);
      acc[1][1] = __builtin_amdgcn_mfma_f32_16x16x32_bf16(a1, b1, acc[1][1], 0, 0, 0);
      acc[0][2] = __builtin_amdgcn_mfma_f32_16x16x32_bf16(a0, b2, acc[0][2], 0, 0, 0);
      acc[1][2] = __builtin_amdgcn_mfma_f32_16x16x32_bf16(a1, b2, acc[1][2], 0, 0, 0);
      acc[0][3] = __builtin_amdgcn_mfma_f32_16x16x32_bf16(a0, b3, acc[0][3], 0, 0, 0);
      acc[1][3] = __builtin_amdgcn_mfma_f32_16x16x32_bf16(a1, b3, acc[1][3], 0, 0, 0);
    }
  }

  // epilogue: C/D layout col=lane&15 (oc), row=(lane>>4)*4+reg (pixel)
  const int rq = lane >> 4;
  float bias[4];
#pragma unroll
  for (int q = 0; q < 4; ++q) bias[q] = beff[q * 16 + ln15];
#pragma unroll
  for (int mf = 0; mf < 2; ++mf) {
#pragma unroll
    for (int q = 0; q < 4; ++q) {
      float4v v = acc[mf][q] + bias[q];
      int oc = q * 16 + ln15;
      float* op = out + (((n * 64 + oc) * 128 + h) * 128 + wbase + mf * 16 + rq * 4);
      *(float4v*)op = v;
    }
  }
}

extern "C" void kernel_launch(void* const* d_in, const int* in_sizes, int n_in,
                              void* d_out, int out_size, void* d_ws, size_t ws_size,
                              hipStream_t stream) {
  const float* x = (const float*)d_in[0];
  const float* w = (const float*)d_in[1];
  const float* b = (const float*)d_in[2];
  const float* wc = (const float*)d_in[3];
  const float* bc = (const float*)d_in[4];
  const float* gate = (const float*)d_in[5];

  // ws layout: wq bf16[9*64*64]=73728B | beff f32[64] @73728 | sums f64[2] @73984
  //            | x_p bf16[16*130*130*64]=34611200B @74240 (16B aligned)
  unsigned short* wq = (unsigned short*)d_ws;
  float* beff = (float*)((char*)d_ws + 73728);
  double* sums = (double*)((char*)d_ws + 73984);
  unsigned short* xp = (unsigned short*)((char*)d_ws + 74240);

  reduce_abs<<<1, 1024, 0, stream>>>(w, wc, sums);
  quant_combine<<<144, 256, 0, stream>>>(w, wc, b, bc, gate, sums, wq, beff);
  transpose_x<<<16 * 130, 256, 0, stream>>>(x, xp);
  conv_mfma<<<2048, 256, 0, stream>>>(xp, wq, beff, (float*)d_out);
}